// Round 6
// baseline (304.723 us; speedup 1.0000x reference)
//
#include <hip/hip_runtime.h>
#include <math.h>

// Problem constants (B=8, N=2048, D_IN=D_V=256, H=8, HD=32, D_FF=512)
#define RTOT 16384   // B*N rows
#define NSEQ 2048
#define NHEAD 8
#define HDIM 32
// Q pre-scale: log2(e)/sqrt(256) so S_mfma = S_true*log2e, softmax via exp2
#define QSCALE 0.09017132252479462f

typedef __attribute__((ext_vector_type(8))) short short8;
typedef __attribute__((ext_vector_type(4))) float f32x4;

#define GLOBAL_AS(p) ((__attribute__((address_space(1))) void*)(p))
#define LDS_AS(p) ((__attribute__((address_space(3))) void*)(p))

__device__ __forceinline__ unsigned pack_bf16(float a, float b) {
  unsigned ua = __float_as_uint(a) + 0x8000u;
  unsigned ub = __float_as_uint(b) + 0x8000u;
  return (ua >> 16) | (ub & 0xffff0000u);
}
// truncating pack (positive values; bias cancels in softmax ratio)
__device__ __forceinline__ unsigned pack_bf16_trunc(float a, float b) {
  return (__float_as_uint(a) >> 16) | (__float_as_uint(b) & 0xffff0000u);
}
__device__ __forceinline__ ushort bf16_1(float a) {
  return (ushort)((__float_as_uint(a) + 0x8000u) >> 16);
}

// ---------------- stage0: fused weight-transpose + cvt(y) + ln0(x) ----------------
// blocks [0,112): weight transpose; [112,4208): y->bf16; [4208,8304): LN0(x)->bf16
__global__ __launch_bounds__(256) void stage0_kernel(
    const float* __restrict__ x, const float* __restrict__ y,
    const float* __restrict__ Wq, const float* __restrict__ Wk,
    const float* __restrict__ Wv, const float* __restrict__ W1,
    const float* __restrict__ W2, const float* __restrict__ ln0g,
    const float* __restrict__ ln0b, ushort* __restrict__ Wqt,
    ushort* __restrict__ Wkt, ushort* __restrict__ Wvt,
    ushort* __restrict__ W1t, ushort* __restrict__ W2t,
    ushort* __restrict__ yh, ushort* __restrict__ xh) {
  const int bid = blockIdx.x;
  const int t = threadIdx.x;
  if (bid < 112) {
    const float* W;
    ushort* Wt;
    int K, N, tile;
    if (bid < 16) { W = Wq; Wt = Wqt; K = 256; N = 256; tile = bid; }
    else if (bid < 32) { W = Wk; Wt = Wkt; K = 256; N = 256; tile = bid - 16; }
    else if (bid < 48) { W = Wv; Wt = Wvt; K = 256; N = 256; tile = bid - 32; }
    else if (bid < 80) { W = W1; Wt = W1t; K = 256; N = 512; tile = bid - 48; }
    else { W = W2; Wt = W2t; K = 512; N = 256; tile = bid - 80; }
    const int tn = N >> 6;
    const int k0 = (tile / tn) << 6, n0 = (tile % tn) << 6;
    __shared__ float T[64][65];
#pragma unroll
    for (int i = 0; i < 16; ++i) {
      const int idx = t + i * 256;
      const int r = idx >> 6, c = idx & 63;
      T[r][c] = W[(size_t)(k0 + r) * N + n0 + c];
    }
    __syncthreads();
#pragma unroll
    for (int i = 0; i < 16; ++i) {
      const int idx = t + i * 256;
      const int r = idx >> 6, c = idx & 63;
      Wt[(size_t)(n0 + r) * K + k0 + c] = bf16_1(T[c][r]);
    }
  } else if (bid < 4208) {
    const size_t i = ((size_t)(bid - 112) * 256 + t) * 4;
    const float4 v = *(const float4*)&y[i];
    uint2 pk;
    pk.x = pack_bf16(v.x, v.y);
    pk.y = pack_bf16(v.z, v.w);
    *(uint2*)&yh[i] = pk;
  } else {
    const int lane = t & 63, wave = t >> 6;
    const size_t row = (size_t)(bid - 4208) * 4 + wave;
    const float* xr = x + row * 256;
    float4 v = *(const float4*)&xr[lane * 4];
    float s = v.x + v.y + v.z + v.w;
#pragma unroll
    for (int m = 1; m < 64; m <<= 1) s += __shfl_xor(s, m, 64);
    const float mu = s * (1.0f / 256.0f);
    const float dx = v.x - mu, dy = v.y - mu, dz = v.z - mu, dw = v.w - mu;
    float ss = dx * dx + dy * dy + dz * dz + dw * dw;
#pragma unroll
    for (int m = 1; m < 64; m <<= 1) ss += __shfl_xor(ss, m, 64);
    const float rstd = rsqrtf(ss * (1.0f / 256.0f) + 1e-5f);
    const float4 gv = *(const float4*)&ln0g[lane * 4];
    const float4 bv = *(const float4*)&ln0b[lane * 4];
    uint2 pk;
    pk.x = pack_bf16(dx * rstd * gv.x + bv.x, dy * rstd * gv.y + bv.y);
    pk.y = pack_bf16(dz * rstd * gv.z + bv.z, dw * rstd * gv.w + bv.w);
    *(uint2*)&xh[row * 256 + lane * 4] = pk;
  }
}

// ---------------- LayerNorm over D=256, bf16 output ----------------
__global__ __launch_bounds__(256) void ln_kernel(
    const float* __restrict__ X, const float* __restrict__ g,
    const float* __restrict__ bt, ushort* __restrict__ Yh) {
  const int lane = threadIdx.x & 63;
  const int wave = threadIdx.x >> 6;
  const size_t row = (size_t)blockIdx.x * 4 + wave;
  const float* xr = X + row * 256;
  float4 v = *(const float4*)&xr[lane * 4];
  float s = v.x + v.y + v.z + v.w;
#pragma unroll
  for (int m = 1; m < 64; m <<= 1) s += __shfl_xor(s, m, 64);
  const float mu = s * (1.0f / 256.0f);
  const float dx = v.x - mu, dy = v.y - mu, dz = v.z - mu, dw = v.w - mu;
  float ss = dx * dx + dy * dy + dz * dz + dw * dw;
#pragma unroll
  for (int m = 1; m < 64; m <<= 1) ss += __shfl_xor(ss, m, 64);
  const float rstd = rsqrtf(ss * (1.0f / 256.0f) + 1e-5f);
  const float4 gv = *(const float4*)&g[lane * 4];
  const float4 bv = *(const float4*)&bt[lane * 4];
  uint2 pk;
  pk.x = pack_bf16(dx * rstd * gv.x + bv.x, dy * rstd * gv.y + bv.y);
  pk.y = pack_bf16(dz * rstd * gv.z + bv.z, dw * rstd * gv.w + bv.w);
  *(uint2*)&Yh[row * 256 + lane * 4] = pk;
}

// ---------------- merged QKV GEMM ----------------
// grid (128, 12): ny>>2 = 0:K 1:V 2:Q ; 128x64 tile, BK=32, 4 waves.
// K: Kh=bf16(v) ; Q: Qf=v, Qh=bf16(v*QSCALE) ; V: transpose -> VhT[b*256+n][nseq]
__global__ __launch_bounds__(256) void qkv_kernel(
    const ushort* __restrict__ xh, const ushort* __restrict__ yh,
    const ushort* __restrict__ Wqt, const ushort* __restrict__ Wkt,
    const ushort* __restrict__ Wvt, const float* __restrict__ bq,
    const float* __restrict__ bk, const float* __restrict__ bv,
    float* __restrict__ Qf, ushort* __restrict__ Qh,
    ushort* __restrict__ Kh, ushort* __restrict__ VhT) {
  __shared__ union UU {
    struct { ushort As[128 * 32]; ushort Bs[64 * 32]; } s;
    ushort Ct[64 * 136];  // V-transpose tile [n_local][m_local]
  } u;
  const int t = threadIdx.x;
  const int lane = t & 63, wave = t >> 6;
  const int l16 = lane & 15, quad = lane >> 4;
  const int row0 = blockIdx.x * 128;
  const int ny = blockIdx.y;
  const int which = ny >> 2;  // 0=K 1=V 2=Q
  const int n0 = (ny & 3) << 6;
  const ushort* A = (which == 2) ? xh : yh;
  const ushort* W = (which == 0) ? Wkt : (which == 1) ? Wvt : Wqt;
  const float* bs = (which == 0) ? bk : (which == 1) ? bv : bq;
  const int mrow = (wave & 1) * 64, ncol = (wave >> 1) * 32;

  const ushort* gA0 = A + (size_t)(row0 + (t >> 2)) * 256 + ((t & 3) << 3);
  const ushort* gA1 = gA0 + (size_t)64 * 256;
  const ushort* gB = W + (size_t)(n0 + (t >> 2)) * 256 + ((t & 3) << 3);
  ushort* lA0 = u.s.As + 8 * t;
  ushort* lA1 = u.s.As + 2048 + 8 * t;
  ushort* lB = u.s.Bs + 8 * t;

  f32x4 acc[4][2] = {};
  for (int kc = 0; kc < 256; kc += 32) {
    __builtin_amdgcn_global_load_lds(GLOBAL_AS(gA0 + kc), LDS_AS(lA0), 16, 0, 0);
    __builtin_amdgcn_global_load_lds(GLOBAL_AS(gA1 + kc), LDS_AS(lA1), 16, 0, 0);
    __builtin_amdgcn_global_load_lds(GLOBAL_AS(gB + kc), LDS_AS(lB), 16, 0, 0);
    __syncthreads();
    short8 af[4], bfr[2];
#pragma unroll
    for (int mi = 0; mi < 4; ++mi)
      af[mi] = *(const short8*)&u.s.As[(mrow + mi * 16 + l16) * 32 + quad * 8];
#pragma unroll
    for (int nj = 0; nj < 2; ++nj)
      bfr[nj] = *(const short8*)&u.s.Bs[(ncol + nj * 16 + l16) * 32 + quad * 8];
#pragma unroll
    for (int mi = 0; mi < 4; ++mi)
#pragma unroll
      for (int nj = 0; nj < 2; ++nj)
        acc[mi][nj] = __builtin_amdgcn_mfma_f32_16x16x32_bf16(
            af[mi], bfr[nj], acc[mi][nj], 0, 0, 0);
    __syncthreads();
  }

  if (which == 1) {
    // V: bias + transpose via LDS, coalesced write to VhT[b*256+n][nseq]
#pragma unroll
    for (int nj = 0; nj < 2; ++nj) {
      const int nloc = ncol + nj * 16 + l16;
      const float bvv = bs[n0 + nloc];
#pragma unroll
      for (int mi = 0; mi < 4; ++mi)
#pragma unroll
        for (int r = 0; r < 4; ++r)
          u.Ct[nloc * 136 + mrow + mi * 16 + quad * 4 + r] =
              bf16_1(acc[mi][nj][r] + bvv);
    }
    __syncthreads();
    const int bb = row0 >> 11, ns0 = row0 & 2047;
#pragma unroll
    for (int i = 0; i < 4; ++i) {
      const int c = t + i * 256;
      const int rr = c >> 4, c8 = (c & 15) << 3;
      *(float4*)&VhT[(size_t)(bb * 256 + n0 + rr) * 2048 + ns0 + c8] =
          *(const float4*)&u.Ct[rr * 136 + c8];
    }
  } else {
#pragma unroll
    for (int nj = 0; nj < 2; ++nj) {
      const int n = n0 + ncol + nj * 16 + l16;
      const float bvv = bs[n];
#pragma unroll
      for (int mi = 0; mi < 4; ++mi) {
#pragma unroll
        for (int r = 0; r < 4; ++r) {
          const size_t m = (size_t)row0 + mrow + mi * 16 + quad * 4 + r;
          const float v = acc[mi][nj][r] + bvv;
          if (which == 2) {
            Qf[m * 256 + n] = v;
            Qh[m * 256 + n] = bf16_1(v * QSCALE);
          } else {
            Kh[m * 256 + n] = bf16_1(v);
          }
        }
      }
    }
  }
}

// ---------------- FFN GEMM: 128x64 tile, BK=32 ----------------
// MODE 2: Ch=bf16(gelu(v)) (FFN1) ; MODE 3: Cf=v+res (FFN2 -> out)
template <int MODE>
__global__ __launch_bounds__(256) void mgemm_kernel(
    const ushort* __restrict__ A, const ushort* __restrict__ Wt,
    const float* __restrict__ bias, const float* __restrict__ res,
    float* __restrict__ Cf, ushort* __restrict__ Ch, int K, int N) {
  __shared__ ushort As[128 * 32];
  __shared__ ushort Bs[64 * 32];
  const int t = threadIdx.x;
  const int lane = t & 63, wave = t >> 6;
  const int l16 = lane & 15, quad = lane >> 4;
  const int row0 = blockIdx.x * 128;
  const int n0 = blockIdx.y << 6;
  const int mrow = (wave & 1) * 64, ncol = (wave >> 1) * 32;

  const ushort* gA0 = A + (size_t)(row0 + (t >> 2)) * K + ((t & 3) << 3);
  const ushort* gA1 = gA0 + (size_t)64 * K;
  const ushort* gB = Wt + (size_t)(n0 + (t >> 2)) * K + ((t & 3) << 3);
  ushort* lA0 = As + 8 * t;
  ushort* lA1 = As + 2048 + 8 * t;
  ushort* lB = Bs + 8 * t;

  f32x4 acc[4][2] = {};
  for (int kc = 0; kc < K; kc += 32) {
    __builtin_amdgcn_global_load_lds(GLOBAL_AS(gA0 + kc), LDS_AS(lA0), 16, 0, 0);
    __builtin_amdgcn_global_load_lds(GLOBAL_AS(gA1 + kc), LDS_AS(lA1), 16, 0, 0);
    __builtin_amdgcn_global_load_lds(GLOBAL_AS(gB + kc), LDS_AS(lB), 16, 0, 0);
    __syncthreads();
    short8 af[4], bfr[2];
#pragma unroll
    for (int mi = 0; mi < 4; ++mi)
      af[mi] = *(const short8*)&As[(mrow + mi * 16 + l16) * 32 + quad * 8];
#pragma unroll
    for (int nj = 0; nj < 2; ++nj)
      bfr[nj] = *(const short8*)&Bs[(ncol + nj * 16 + l16) * 32 + quad * 8];
#pragma unroll
    for (int mi = 0; mi < 4; ++mi)
#pragma unroll
      for (int nj = 0; nj < 2; ++nj)
        acc[mi][nj] = __builtin_amdgcn_mfma_f32_16x16x32_bf16(
            af[mi], bfr[nj], acc[mi][nj], 0, 0, 0);
    __syncthreads();
  }
#pragma unroll
  for (int nj = 0; nj < 2; ++nj) {
    const int n = n0 + ncol + nj * 16 + l16;
    const float bvv = bias[n];
#pragma unroll
    for (int mi = 0; mi < 4; ++mi) {
#pragma unroll
      for (int r = 0; r < 4; ++r) {
        const size_t m = (size_t)row0 + mrow + mi * 16 + quad * 4 + r;
        float v = acc[mi][nj][r] + bvv;
        if (MODE == 2) {
          v = 0.5f * v * (1.0f + erff(v * 0.70710678118654752f));
          Ch[m * N + n] = bf16_1(v);
        }
        if (MODE == 3) Cf[m * N + n] = v + res[m * N + n];
      }
    }
  }
}

// ---------------- Flash attention (bf16 MFMA, static-max, K direct-load) ----------------
// O = Qf + softmax(Q K^T / 16) V. Static max 8 in MFMA C-init; l via ones-MFMA.
// K fragments loaded directly from global (A-frag pattern, register dbuf);
// V cooperatively staged from VhT[b*256+h*32+d][nseq] (B-frag layout).
__global__ __launch_bounds__(256, 4) void attn_kernel(
    const float* __restrict__ Qf, const ushort* __restrict__ Qh,
    const ushort* __restrict__ Kh, const ushort* __restrict__ VhT,
    float* __restrict__ O) {
  __shared__ ushort Vt[2][32][72];
  __shared__ ushort Pl[4][16][72];

  const int t = threadIdx.x;
  const int lane = t & 63, wave = t >> 6;
  const int l16 = lane & 15, quad = lane >> 4;
  const int bh = blockIdx.x & 63;
  const int qt = blockIdx.x >> 6;
  const int b = bh >> 3, h = bh & 7;

  const size_t rowQ = (size_t)(b * NSEQ + qt * 64 + wave * 16 + l16);
  const short8 qfrag = *(const short8*)&Qh[rowQ * 256 + h * HDIM + quad * 8];
  const short8 ones = {16256, 16256, 16256, 16256,
                       16256, 16256, 16256, 16256};  // bf16 1.0 x8
  const f32x4 cinit = {-8.f, -8.f, -8.f, -8.f};

  f32x4 oacc0 = {0.f, 0.f, 0.f, 0.f}, oacc1 = {0.f, 0.f, 0.f, 0.f};
  f32x4 oaccS = {0.f, 0.f, 0.f, 0.f};

  // K direct A-frag base: lane (l16,quad), sub s -> row b*N + kt*64 + s*16 + l16
  const ushort* gK = Kh + ((size_t)(b * NSEQ) + l16) * 256 + h * HDIM + quad * 8;
  // V cooperative staging: thread -> (d = t>>3, cols (t&7)*8)
  const int vd = t >> 3, vc8 = (t & 7) << 3;
  const ushort* gV = VhT + ((size_t)(bh * 32) + vd) * 2048 + vc8;

  short8 kcur[4], knxt[4];
#pragma unroll
  for (int sub = 0; sub < 4; ++sub)
    kcur[sub] = *(const short8*)(gK + (size_t)(sub * 16) * 256);
  float4 vreg = *(const float4*)gV;

  for (int kt = 0; kt < 32; ++kt) {
    const int bf = kt & 1;
    *(float4*)&Vt[bf][vd][vc8] = vreg;
    __syncthreads();  // V buf visible; prev readers of this buf done (prev barrier)
    if (kt < 31) {    // register prefetch of next K/V tiles, in flight over compute
      vreg = *(const float4*)(gV + (kt + 1) * 64);
#pragma unroll
      for (int sub = 0; sub < 4; ++sub)
        knxt[sub] =
            *(const short8*)(gK + (size_t)((kt + 1) * 64 + sub * 16) * 256);
    }

    // S^T = K Q^T - 8 : lane holds P[q=l16][kc=sub*16+quad*4+r]
    f32x4 sa[4];
#pragma unroll
    for (int sub = 0; sub < 4; ++sub)
      sa[sub] =
          __builtin_amdgcn_mfma_f32_16x16x32_bf16(kcur[sub], qfrag, cinit, 0, 0, 0);
    // p = exp2(S - 8); truncating pack; wave-private LDS round trip
#pragma unroll
    for (int sub = 0; sub < 4; ++sub) {
      float p0 = __builtin_amdgcn_exp2f(sa[sub][0]);
      float p1 = __builtin_amdgcn_exp2f(sa[sub][1]);
      float p2 = __builtin_amdgcn_exp2f(sa[sub][2]);
      float p3 = __builtin_amdgcn_exp2f(sa[sub][3]);
      uint2 pk;
      pk.x = pack_bf16_trunc(p0, p1);
      pk.y = pack_bf16_trunc(p2, p3);
      *(uint2*)&Pl[wave][l16][sub * 16 + quad * 4] = pk;
    }
    __threadfence_block();  // lgkmcnt drain; Pl is wave-private

    const short8 pf0 = *(const short8*)&Pl[wave][l16][quad * 8];
    const short8 pf1 = *(const short8*)&Pl[wave][l16][32 + quad * 8];
    const short8 vf00 = *(const short8*)&Vt[bf][l16][quad * 8];
    const short8 vf01 = *(const short8*)&Vt[bf][l16][32 + quad * 8];
    const short8 vf10 = *(const short8*)&Vt[bf][16 + l16][quad * 8];
    const short8 vf11 = *(const short8*)&Vt[bf][16 + l16][32 + quad * 8];
    oacc0 = __builtin_amdgcn_mfma_f32_16x16x32_bf16(pf0, vf00, oacc0, 0, 0, 0);
    oacc0 = __builtin_amdgcn_mfma_f32_16x16x32_bf16(pf1, vf01, oacc0, 0, 0, 0);
    oacc1 = __builtin_amdgcn_mfma_f32_16x16x32_bf16(pf0, vf10, oacc1, 0, 0, 0);
    oacc1 = __builtin_amdgcn_mfma_f32_16x16x32_bf16(pf1, vf11, oacc1, 0, 0, 0);
    oaccS = __builtin_amdgcn_mfma_f32_16x16x32_bf16(pf0, ones, oaccS, 0, 0, 0);
    oaccS = __builtin_amdgcn_mfma_f32_16x16x32_bf16(pf1, ones, oaccS, 0, 0, 0);

#pragma unroll
    for (int sub = 0; sub < 4; ++sub) kcur[sub] = knxt[sub];
  }

  // epilogue: O[q=quad*4+r][d=l16 / l16+16]; l for row quad*4+r is oaccS[r]
  const size_t row0 = (size_t)(b * NSEQ + qt * 64 + wave * 16 + quad * 4);
#pragma unroll
  for (int r = 0; r < 4; ++r) {
    const float il = 1.0f / oaccS[r];
    const size_t ro = (row0 + r) * 256 + h * HDIM + l16;
    O[ro] = Qf[ro] + oacc0[r] * il;
    O[ro + 16] = Qf[ro + 16] + oacc1[r] * il;
  }
}

extern "C" void kernel_launch(void* const* d_in, const int* in_sizes, int n_in,
                              void* d_out, int out_size, void* d_ws, size_t ws_size,
                              hipStream_t stream) {
  const float* x = (const float*)d_in[0];
  const float* y = (const float*)d_in[1];
  const float* Wq = (const float*)d_in[2];
  const float* bq = (const float*)d_in[3];
  const float* Wk = (const float*)d_in[4];
  const float* bk = (const float*)d_in[5];
  const float* Wv = (const float*)d_in[6];
  const float* bv = (const float*)d_in[7];
  const float* W1 = (const float*)d_in[8];
  const float* b1 = (const float*)d_in[9];
  const float* W2 = (const float*)d_in[10];
  const float* b2 = (const float*)d_in[11];
  const float* ln0g = (const float*)d_in[12];
  const float* ln0b = (const float*)d_in[13];
  const float* ln1g = (const float*)d_in[14];
  const float* ln1b = (const float*)d_in[15];
  float* out = (float*)d_out;
  char* base = (char*)d_ws;

  const size_t RM = (size_t)RTOT * 256;
  // region0: yh (bf16, stage0->qkv) then overwritten by Ob (fp32, attn out)
  ushort* yh = (ushort*)base;
  float* Ob = (float*)base;
  float* Qf = (float*)(base + RM * 4);
  ushort* Qh = (ushort*)(base + 2 * RM * 4);
  ushort* Kh = (ushort*)(base + 2 * RM * 4 + RM * 2);
  ushort* VhT = (ushort*)(base + 3 * RM * 4);
  ushort* xh = (ushort*)(base + 3 * RM * 4 + RM * 2);  // LN0 out; reused as On
  ushort* Onh = xh;
  ushort* Hidh = Qh;  // [R,512] bf16 overlays Qh+Kh (dead after attn)
  char* wbase = base + 4 * RM * 4;
  ushort* Wqt = (ushort*)wbase;  // [256,256]
  ushort* Wkt = Wqt + 65536;
  ushort* Wvt = Wkt + 65536;
  ushort* W1t = Wvt + 65536;   // [512,256]
  ushort* W2t = W1t + 131072;  // [256,512]

  stage0_kernel<<<8304, 256, 0, stream>>>(x, y, Wq, Wk, Wv, W1, W2, ln0g, ln0b,
                                          Wqt, Wkt, Wvt, W1t, W2t, yh, xh);
  qkv_kernel<<<dim3(128, 12), 256, 0, stream>>>(xh, yh, Wqt, Wkt, Wvt, bq, bk,
                                                bv, Qf, Qh, Kh, VhT);
  attn_kernel<<<2048, 256, 0, stream>>>(Qf, Qh, Kh, VhT, Ob);
  ln_kernel<<<RTOT / 4, 256, 0, stream>>>(Ob, ln1g, ln1b, Onh);
  mgemm_kernel<2><<<dim3(128, 8), 256, 0, stream>>>(Onh, W1t, b1, nullptr,
                                                    nullptr, Hidh, 256, 512);
  mgemm_kernel<3><<<dim3(128, 4), 256, 0, stream>>>(Hidh, W2t, b2, Ob, out,
                                                    nullptr, 512, 256);
}

// Round 7
// 226.499 us; speedup vs baseline: 1.3454x; 1.3454x over previous
//
#include <hip/hip_runtime.h>
#include <math.h>

// Problem constants (B=8, N=2048, D_IN=D_V=256, H=8, HD=32, D_FF=512)
#define RTOT 16384   // B*N rows
#define NSEQ 2048
#define NHEAD 8
#define HDIM 32
// Q pre-scale: log2(e)/sqrt(256) so S_mfma = S_true*log2e, softmax via exp2
#define QSCALE 0.09017132252479462f
#define QINV (1.0f / QSCALE)

typedef __attribute__((ext_vector_type(8))) short short8;
typedef __attribute__((ext_vector_type(4))) float f32x4;

#define GLOBAL_AS(p) ((__attribute__((address_space(1))) void*)(p))
#define LDS_AS(p) ((__attribute__((address_space(3))) void*)(p))

__device__ __forceinline__ unsigned pack_bf16(float a, float b) {
  unsigned ua = __float_as_uint(a) + 0x8000u;
  unsigned ub = __float_as_uint(b) + 0x8000u;
  return (ua >> 16) | (ub & 0xffff0000u);
}
// truncating pack (positive values; bias cancels in softmax ratio)
__device__ __forceinline__ unsigned pack_bf16_trunc(float a, float b) {
  return (__float_as_uint(a) >> 16) | (__float_as_uint(b) & 0xffff0000u);
}
__device__ __forceinline__ ushort bf16_1(float a) {
  return (ushort)((__float_as_uint(a) + 0x8000u) >> 16);
}
__device__ __forceinline__ float bf16_to_f(ushort u) {
  return __uint_as_float(((unsigned)u) << 16);
}

// ---------------- stage0: fused weight-transpose + cvt(y) + ln0(x) ----------------
// blocks [0,112): weight transpose; [112,4208): y->bf16; [4208,8304): LN0(x)->bf16
__global__ __launch_bounds__(256) void stage0_kernel(
    const float* __restrict__ x, const float* __restrict__ y,
    const float* __restrict__ Wq, const float* __restrict__ Wk,
    const float* __restrict__ Wv, const float* __restrict__ W1,
    const float* __restrict__ W2, const float* __restrict__ ln0g,
    const float* __restrict__ ln0b, ushort* __restrict__ Wqt,
    ushort* __restrict__ Wkt, ushort* __restrict__ Wvt,
    ushort* __restrict__ W1t, ushort* __restrict__ W2t,
    ushort* __restrict__ yh, ushort* __restrict__ xh) {
  const int bid = blockIdx.x;
  const int t = threadIdx.x;
  if (bid < 112) {
    const float* W;
    ushort* Wt;
    int K, N, tile;
    if (bid < 16) { W = Wq; Wt = Wqt; K = 256; N = 256; tile = bid; }
    else if (bid < 32) { W = Wk; Wt = Wkt; K = 256; N = 256; tile = bid - 16; }
    else if (bid < 48) { W = Wv; Wt = Wvt; K = 256; N = 256; tile = bid - 32; }
    else if (bid < 80) { W = W1; Wt = W1t; K = 256; N = 512; tile = bid - 48; }
    else { W = W2; Wt = W2t; K = 512; N = 256; tile = bid - 80; }
    const int tn = N >> 6;
    const int k0 = (tile / tn) << 6, n0 = (tile % tn) << 6;
    __shared__ float T[64][65];
#pragma unroll
    for (int i = 0; i < 16; ++i) {
      const int idx = t + i * 256;
      const int r = idx >> 6, c = idx & 63;
      T[r][c] = W[(size_t)(k0 + r) * N + n0 + c];
    }
    __syncthreads();
#pragma unroll
    for (int i = 0; i < 16; ++i) {
      const int idx = t + i * 256;
      const int r = idx >> 6, c = idx & 63;
      Wt[(size_t)(n0 + r) * K + k0 + c] = bf16_1(T[c][r]);
    }
  } else if (bid < 4208) {
    const size_t i = ((size_t)(bid - 112) * 256 + t) * 4;
    const float4 v = *(const float4*)&y[i];
    uint2 pk;
    pk.x = pack_bf16(v.x, v.y);
    pk.y = pack_bf16(v.z, v.w);
    *(uint2*)&yh[i] = pk;
  } else {
    const int lane = t & 63, wave = t >> 6;
    const size_t row = (size_t)(bid - 4208) * 4 + wave;
    const float* xr = x + row * 256;
    float4 v = *(const float4*)&xr[lane * 4];
    float s = v.x + v.y + v.z + v.w;
#pragma unroll
    for (int m = 1; m < 64; m <<= 1) s += __shfl_xor(s, m, 64);
    const float mu = s * (1.0f / 256.0f);
    const float dx = v.x - mu, dy = v.y - mu, dz = v.z - mu, dw = v.w - mu;
    float ss = dx * dx + dy * dy + dz * dz + dw * dw;
#pragma unroll
    for (int m = 1; m < 64; m <<= 1) ss += __shfl_xor(ss, m, 64);
    const float rstd = rsqrtf(ss * (1.0f / 256.0f) + 1e-5f);
    const float4 gv = *(const float4*)&ln0g[lane * 4];
    const float4 bv = *(const float4*)&ln0b[lane * 4];
    uint2 pk;
    pk.x = pack_bf16(dx * rstd * gv.x + bv.x, dy * rstd * gv.y + bv.y);
    pk.y = pack_bf16(dz * rstd * gv.z + bv.z, dw * rstd * gv.w + bv.w);
    *(uint2*)&xh[row * 256 + lane * 4] = pk;
  }
}

// ---------------- LayerNorm over D=256, bf16 output ----------------
__global__ __launch_bounds__(256) void ln_kernel(
    const float* __restrict__ X, const float* __restrict__ g,
    const float* __restrict__ bt, ushort* __restrict__ Yh) {
  const int lane = threadIdx.x & 63;
  const int wave = threadIdx.x >> 6;
  const size_t row = (size_t)blockIdx.x * 4 + wave;
  const float* xr = X + row * 256;
  float4 v = *(const float4*)&xr[lane * 4];
  float s = v.x + v.y + v.z + v.w;
#pragma unroll
  for (int m = 1; m < 64; m <<= 1) s += __shfl_xor(s, m, 64);
  const float mu = s * (1.0f / 256.0f);
  const float dx = v.x - mu, dy = v.y - mu, dz = v.z - mu, dw = v.w - mu;
  float ss = dx * dx + dy * dy + dz * dz + dw * dw;
#pragma unroll
  for (int m = 1; m < 64; m <<= 1) ss += __shfl_xor(ss, m, 64);
  const float rstd = rsqrtf(ss * (1.0f / 256.0f) + 1e-5f);
  const float4 gv = *(const float4*)&g[lane * 4];
  const float4 bv = *(const float4*)&bt[lane * 4];
  uint2 pk;
  pk.x = pack_bf16(dx * rstd * gv.x + bv.x, dy * rstd * gv.y + bv.y);
  pk.y = pack_bf16(dz * rstd * gv.z + bv.z, dw * rstd * gv.w + bv.w);
  *(uint2*)&Yh[row * 256 + lane * 4] = pk;
}

// ---------------- merged QKV GEMM ----------------
// grid (128, 12): ny>>2 = 0:K 1:V 2:Q ; 128x64 tile, BK=32, 4 waves.
// K: Kh=bf16(v) ; Q: Qh=bf16(v*QSCALE) ; V: transpose -> VhT[b*256+n][nseq]
__global__ __launch_bounds__(256) void qkv_kernel(
    const ushort* __restrict__ xh, const ushort* __restrict__ yh,
    const ushort* __restrict__ Wqt, const ushort* __restrict__ Wkt,
    const ushort* __restrict__ Wvt, const float* __restrict__ bq,
    const float* __restrict__ bk, const float* __restrict__ bv,
    ushort* __restrict__ Qh, ushort* __restrict__ Kh,
    ushort* __restrict__ VhT) {
  __shared__ union UU {
    struct { ushort As[128 * 32]; ushort Bs[64 * 32]; } s;
    ushort Ct[64 * 136];  // V-transpose tile [n_local][m_local]
  } u;
  const int t = threadIdx.x;
  const int lane = t & 63, wave = t >> 6;
  const int l16 = lane & 15, quad = lane >> 4;
  const int row0 = blockIdx.x * 128;
  const int ny = blockIdx.y;
  const int which = ny >> 2;  // 0=K 1=V 2=Q
  const int n0 = (ny & 3) << 6;
  const ushort* A = (which == 2) ? xh : yh;
  const ushort* W = (which == 0) ? Wkt : (which == 1) ? Wvt : Wqt;
  const float* bs = (which == 0) ? bk : (which == 1) ? bv : bq;
  const int mrow = (wave & 1) * 64, ncol = (wave >> 1) * 32;

  const ushort* gA0 = A + (size_t)(row0 + (t >> 2)) * 256 + ((t & 3) << 3);
  const ushort* gA1 = gA0 + (size_t)64 * 256;
  const ushort* gB = W + (size_t)(n0 + (t >> 2)) * 256 + ((t & 3) << 3);
  ushort* lA0 = u.s.As + 8 * t;
  ushort* lA1 = u.s.As + 2048 + 8 * t;
  ushort* lB = u.s.Bs + 8 * t;

  f32x4 acc[4][2] = {};
  for (int kc = 0; kc < 256; kc += 32) {
    __builtin_amdgcn_global_load_lds(GLOBAL_AS(gA0 + kc), LDS_AS(lA0), 16, 0, 0);
    __builtin_amdgcn_global_load_lds(GLOBAL_AS(gA1 + kc), LDS_AS(lA1), 16, 0, 0);
    __builtin_amdgcn_global_load_lds(GLOBAL_AS(gB + kc), LDS_AS(lB), 16, 0, 0);
    __syncthreads();
    short8 af[4], bfr[2];
#pragma unroll
    for (int mi = 0; mi < 4; ++mi)
      af[mi] = *(const short8*)&u.s.As[(mrow + mi * 16 + l16) * 32 + quad * 8];
#pragma unroll
    for (int nj = 0; nj < 2; ++nj)
      bfr[nj] = *(const short8*)&u.s.Bs[(ncol + nj * 16 + l16) * 32 + quad * 8];
#pragma unroll
    for (int mi = 0; mi < 4; ++mi)
#pragma unroll
      for (int nj = 0; nj < 2; ++nj)
        acc[mi][nj] = __builtin_amdgcn_mfma_f32_16x16x32_bf16(
            af[mi], bfr[nj], acc[mi][nj], 0, 0, 0);
    __syncthreads();
  }

  if (which == 1) {
    // V: bias + transpose via LDS, coalesced write to VhT[b*256+n][nseq]
#pragma unroll
    for (int nj = 0; nj < 2; ++nj) {
      const int nloc = ncol + nj * 16 + l16;
      const float bvv = bs[n0 + nloc];
#pragma unroll
      for (int mi = 0; mi < 4; ++mi)
#pragma unroll
        for (int r = 0; r < 4; ++r)
          u.Ct[nloc * 136 + mrow + mi * 16 + quad * 4 + r] =
              bf16_1(acc[mi][nj][r] + bvv);
    }
    __syncthreads();
    const int bb = row0 >> 11, ns0 = row0 & 2047;
#pragma unroll
    for (int i = 0; i < 4; ++i) {
      const int c = t + i * 256;
      const int rr = c >> 4, c8 = (c & 15) << 3;
      *(float4*)&VhT[(size_t)(bb * 256 + n0 + rr) * 2048 + ns0 + c8] =
          *(const float4*)&u.Ct[rr * 136 + c8];
    }
  } else {
#pragma unroll
    for (int nj = 0; nj < 2; ++nj) {
      const int n = n0 + ncol + nj * 16 + l16;
      const float bvv = bs[n];
#pragma unroll
      for (int mi = 0; mi < 4; ++mi) {
#pragma unroll
        for (int r = 0; r < 4; ++r) {
          const size_t m = (size_t)row0 + mrow + mi * 16 + quad * 4 + r;
          const float v = acc[mi][nj][r] + bvv;
          if (which == 2) Qh[m * 256 + n] = bf16_1(v * QSCALE);
          else Kh[m * 256 + n] = bf16_1(v);
        }
      }
    }
  }
}

// ---------------- FFN GEMM: 128x64 tile, BK=32 ----------------
// MODE 2: Ch=bf16(gelu(v)) (FFN1) ; MODE 3: Cf=v+res (FFN2 -> out)
template <int MODE>
__global__ __launch_bounds__(256) void mgemm_kernel(
    const ushort* __restrict__ A, const ushort* __restrict__ Wt,
    const float* __restrict__ bias, const float* __restrict__ res,
    float* __restrict__ Cf, ushort* __restrict__ Ch, int K, int N) {
  __shared__ ushort As[128 * 32];
  __shared__ ushort Bs[64 * 32];
  const int t = threadIdx.x;
  const int lane = t & 63, wave = t >> 6;
  const int l16 = lane & 15, quad = lane >> 4;
  const int row0 = blockIdx.x * 128;
  const int n0 = blockIdx.y << 6;
  const int mrow = (wave & 1) * 64, ncol = (wave >> 1) * 32;

  const ushort* gA0 = A + (size_t)(row0 + (t >> 2)) * K + ((t & 3) << 3);
  const ushort* gA1 = gA0 + (size_t)64 * K;
  const ushort* gB = Wt + (size_t)(n0 + (t >> 2)) * K + ((t & 3) << 3);
  ushort* lA0 = As + 8 * t;
  ushort* lA1 = As + 2048 + 8 * t;
  ushort* lB = Bs + 8 * t;

  f32x4 acc[4][2] = {};
  for (int kc = 0; kc < K; kc += 32) {
    __builtin_amdgcn_global_load_lds(GLOBAL_AS(gA0 + kc), LDS_AS(lA0), 16, 0, 0);
    __builtin_amdgcn_global_load_lds(GLOBAL_AS(gA1 + kc), LDS_AS(lA1), 16, 0, 0);
    __builtin_amdgcn_global_load_lds(GLOBAL_AS(gB + kc), LDS_AS(lB), 16, 0, 0);
    __syncthreads();
    short8 af[4], bfr[2];
#pragma unroll
    for (int mi = 0; mi < 4; ++mi)
      af[mi] = *(const short8*)&As[(mrow + mi * 16 + l16) * 32 + quad * 8];
#pragma unroll
    for (int nj = 0; nj < 2; ++nj)
      bfr[nj] = *(const short8*)&Bs[(ncol + nj * 16 + l16) * 32 + quad * 8];
#pragma unroll
    for (int mi = 0; mi < 4; ++mi)
#pragma unroll
      for (int nj = 0; nj < 2; ++nj)
        acc[mi][nj] = __builtin_amdgcn_mfma_f32_16x16x32_bf16(
            af[mi], bfr[nj], acc[mi][nj], 0, 0, 0);
    __syncthreads();
  }
#pragma unroll
  for (int nj = 0; nj < 2; ++nj) {
    const int n = n0 + ncol + nj * 16 + l16;
    const float bvv = bias[n];
#pragma unroll
    for (int mi = 0; mi < 4; ++mi) {
#pragma unroll
      for (int r = 0; r < 4; ++r) {
        const size_t m = (size_t)row0 + mrow + mi * 16 + quad * 4 + r;
        float v = acc[mi][nj][r] + bvv;
        if (MODE == 2) {
          v = 0.5f * v * (1.0f + erff(v * 0.70710678118654752f));
          Ch[m * N + n] = bf16_1(v);
        }
        if (MODE == 3) Cf[m * N + n] = v + res[m * N + n];
      }
    }
  }
}

// ---------------- Flash attention (bf16 MFMA, static-max, 128q blocks) ----------------
// O = Q + softmax(Q K^T / 16) V.  Qh pre-scaled by log2(e)/16 (bf16); residual
// recovered as Qh/QSCALE. Static max 8 in MFMA C-init; l via ones-MFMA.
// Block: 128 q rows; wave handles 2 groups of 16 q rows, kf/vf frags reused.
// Grid 1024: bh = idx&63 (XCD swizzle), qt = idx>>6.
__global__ __launch_bounds__(256) void attn_kernel(
    const ushort* __restrict__ Qh, const ushort* __restrict__ Kh,
    const ushort* __restrict__ VhT, float* __restrict__ O) {
  __shared__ ushort Ks[2][64][40];      // 10240 B
  __shared__ ushort Vt[2][32][72];      // 9216 B
  __shared__ ushort Pl[4][2][16][72];   // 18432 B  (per-wave, per-group)

  const int t = threadIdx.x;
  const int lane = t & 63, wave = t >> 6;
  const int l16 = lane & 15, quad = lane >> 4;
  const int bh = blockIdx.x & 63;
  const int qt = blockIdx.x >> 6;  // 0..15
  const int b = bh >> 3, h = bh & 7;

  const size_t rowQ0 = (size_t)(b * NSEQ + qt * 128 + wave * 32 + l16);
  const short8 qfrag0 = *(const short8*)&Qh[rowQ0 * 256 + h * HDIM + quad * 8];
  const short8 qfrag1 =
      *(const short8*)&Qh[(rowQ0 + 16) * 256 + h * HDIM + quad * 8];
  const short8 ones = {16256, 16256, 16256, 16256,
                       16256, 16256, 16256, 16256};  // bf16 1.0 x8
  const f32x4 cinit = {-8.f, -8.f, -8.f, -8.f};

  f32x4 o00 = {0.f, 0.f, 0.f, 0.f}, o01 = {0.f, 0.f, 0.f, 0.f};
  f32x4 o10 = {0.f, 0.f, 0.f, 0.f}, o11 = {0.f, 0.f, 0.f, 0.f};
  f32x4 s0 = {0.f, 0.f, 0.f, 0.f}, s1 = {0.f, 0.f, 0.f, 0.f};

  // staging coords (cooperative, coalesced): K tile [64][32], V tile [32][64]
  const int kr = t >> 2, kc8 = (t & 3) << 3;
  const int vd = t >> 3, vc8 = (t & 7) << 3;
  const ushort* gK = Kh + ((size_t)(b * NSEQ + kr)) * 256 + h * HDIM + kc8;
  const ushort* gV = VhT + ((size_t)(bh * 32 + vd)) * 2048 + vc8;

  float4 kreg = *(const float4*)gK;
  float4 vreg = *(const float4*)gV;

  for (int kt = 0; kt < 32; ++kt) {
    const int bf = kt & 1;
    *(float4*)&Ks[bf][kr][kc8] = kreg;
    *(float4*)&Vt[bf][vd][vc8] = vreg;
    __syncthreads();  // buf visible; prev readers done (prev barrier)
    if (kt < 31) {    // register prefetch, in flight over compute
      kreg = *(const float4*)(gK + (size_t)(kt + 1) * 64 * 256);
      vreg = *(const float4*)(gV + (kt + 1) * 64);
    }

    // shared fragments for both q-groups (registers)
    short8 kf[4];
#pragma unroll
    for (int sub = 0; sub < 4; ++sub)
      kf[sub] = *(const short8*)&Ks[bf][sub * 16 + l16][quad * 8];
    const short8 vf00 = *(const short8*)&Vt[bf][l16][quad * 8];
    const short8 vf01 = *(const short8*)&Vt[bf][l16][32 + quad * 8];
    const short8 vf10 = *(const short8*)&Vt[bf][16 + l16][quad * 8];
    const short8 vf11 = *(const short8*)&Vt[bf][16 + l16][32 + quad * 8];

    // ---- group 0 ----
    {
      f32x4 sa[4];
#pragma unroll
      for (int sub = 0; sub < 4; ++sub)
        sa[sub] = __builtin_amdgcn_mfma_f32_16x16x32_bf16(kf[sub], qfrag0,
                                                          cinit, 0, 0, 0);
#pragma unroll
      for (int sub = 0; sub < 4; ++sub) {
        float p0 = __builtin_amdgcn_exp2f(sa[sub][0]);
        float p1 = __builtin_amdgcn_exp2f(sa[sub][1]);
        float p2 = __builtin_amdgcn_exp2f(sa[sub][2]);
        float p3 = __builtin_amdgcn_exp2f(sa[sub][3]);
        uint2 pk;
        pk.x = pack_bf16_trunc(p0, p1);
        pk.y = pack_bf16_trunc(p2, p3);
        *(uint2*)&Pl[wave][0][l16][sub * 16 + quad * 4] = pk;
      }
      __threadfence_block();
      const short8 pf0 = *(const short8*)&Pl[wave][0][l16][quad * 8];
      const short8 pf1 = *(const short8*)&Pl[wave][0][l16][32 + quad * 8];
      o00 = __builtin_amdgcn_mfma_f32_16x16x32_bf16(pf0, vf00, o00, 0, 0, 0);
      o00 = __builtin_amdgcn_mfma_f32_16x16x32_bf16(pf1, vf01, o00, 0, 0, 0);
      o01 = __builtin_amdgcn_mfma_f32_16x16x32_bf16(pf0, vf10, o01, 0, 0, 0);
      o01 = __builtin_amdgcn_mfma_f32_16x16x32_bf16(pf1, vf11, o01, 0, 0, 0);
      s0 = __builtin_amdgcn_mfma_f32_16x16x32_bf16(pf0, ones, s0, 0, 0, 0);
      s0 = __builtin_amdgcn_mfma_f32_16x16x32_bf16(pf1, ones, s0, 0, 0, 0);
    }
    // ---- group 1 ----
    {
      f32x4 sa[4];
#pragma unroll
      for (int sub = 0; sub < 4; ++sub)
        sa[sub] = __builtin_amdgcn_mfma_f32_16x16x32_bf16(kf[sub], qfrag1,
                                                          cinit, 0, 0, 0);
#pragma unroll
      for (int sub = 0; sub < 4; ++sub) {
        float p0 = __builtin_amdgcn_exp2f(sa[sub][0]);
        float p1 = __builtin_amdgcn_exp2f(sa[sub][1]);
        float p2 = __builtin_amdgcn_exp2f(sa[sub][2]);
        float p3 = __builtin_amdgcn_exp2f(sa[sub][3]);
        uint2 pk;
        pk.x = pack_bf16_trunc(p0, p1);
        pk.y = pack_bf16_trunc(p2, p3);
        *(uint2*)&Pl[wave][1][l16][sub * 16 + quad * 4] = pk;
      }
      __threadfence_block();
      const short8 pf0 = *(const short8*)&Pl[wave][1][l16][quad * 8];
      const short8 pf1 = *(const short8*)&Pl[wave][1][l16][32 + quad * 8];
      o10 = __builtin_amdgcn_mfma_f32_16x16x32_bf16(pf0, vf00, o10, 0, 0, 0);
      o10 = __builtin_amdgcn_mfma_f32_16x16x32_bf16(pf1, vf01, o10, 0, 0, 0);
      o11 = __builtin_amdgcn_mfma_f32_16x16x32_bf16(pf0, vf10, o11, 0, 0, 0);
      o11 = __builtin_amdgcn_mfma_f32_16x16x32_bf16(pf1, vf11, o11, 0, 0, 0);
      s1 = __builtin_amdgcn_mfma_f32_16x16x32_bf16(pf0, ones, s1, 0, 0, 0);
      s1 = __builtin_amdgcn_mfma_f32_16x16x32_bf16(pf1, ones, s1, 0, 0, 0);
    }
  }

  // ---- epilogue: O = Q + oacc/l ; Q routed via wave-private LDS ----
  __threadfence_block();
  *(short8*)&Pl[wave][0][l16][quad * 8] = qfrag0;
  *(short8*)&Pl[wave][1][l16][quad * 8] = qfrag1;
  __threadfence_block();
#pragma unroll
  for (int g = 0; g < 2; ++g) {
    const f32x4 oS = g ? s1 : s0;
    const f32x4 oa = g ? o10 : o00;
    const f32x4 ob = g ? o11 : o01;
    const size_t row0 =
        (size_t)(b * NSEQ + qt * 128 + wave * 32 + g * 16 + quad * 4);
#pragma unroll
    for (int r = 0; r < 4; ++r) {
      const float q0 = bf16_to_f(Pl[wave][g][quad * 4 + r][l16]) * QINV;
      const float q1 = bf16_to_f(Pl[wave][g][quad * 4 + r][16 + l16]) * QINV;
      const float il = 1.0f / oS[r];
      const size_t ro = (row0 + r) * 256 + h * HDIM + l16;
      O[ro] = q0 + oa[r] * il;
      O[ro + 16] = q1 + ob[r] * il;
    }
  }
}

extern "C" void kernel_launch(void* const* d_in, const int* in_sizes, int n_in,
                              void* d_out, int out_size, void* d_ws, size_t ws_size,
                              hipStream_t stream) {
  const float* x = (const float*)d_in[0];
  const float* y = (const float*)d_in[1];
  const float* Wq = (const float*)d_in[2];
  const float* bq = (const float*)d_in[3];
  const float* Wk = (const float*)d_in[4];
  const float* bk = (const float*)d_in[5];
  const float* Wv = (const float*)d_in[6];
  const float* bv = (const float*)d_in[7];
  const float* W1 = (const float*)d_in[8];
  const float* b1 = (const float*)d_in[9];
  const float* W2 = (const float*)d_in[10];
  const float* b2 = (const float*)d_in[11];
  const float* ln0g = (const float*)d_in[12];
  const float* ln0b = (const float*)d_in[13];
  const float* ln1g = (const float*)d_in[14];
  const float* ln1b = (const float*)d_in[15];
  float* out = (float*)d_out;
  char* base = (char*)d_ws;

  const size_t RM = (size_t)RTOT * 256;
  // region0: yh (bf16, stage0->qkv) then overwritten by Ob (fp32, attn out)
  ushort* yh = (ushort*)base;
  float* Ob = (float*)base;
  ushort* Qh = (ushort*)(base + 2 * RM * 4);
  ushort* Kh = (ushort*)(base + 2 * RM * 4 + RM * 2);
  ushort* VhT = (ushort*)(base + 3 * RM * 4);
  ushort* xh = (ushort*)(base + 3 * RM * 4 + RM * 2);  // LN0 out; reused as On
  ushort* Onh = xh;
  ushort* Hidh = Qh;  // [R,512] bf16 overlays Qh+Kh (dead after attn)
  char* wbase = base + 4 * RM * 4;
  ushort* Wqt = (ushort*)wbase;  // [256,256]
  ushort* Wkt = Wqt + 65536;
  ushort* Wvt = Wkt + 65536;
  ushort* W1t = Wvt + 65536;   // [512,256]
  ushort* W2t = W1t + 131072;  // [256,512]

  stage0_kernel<<<8304, 256, 0, stream>>>(x, y, Wq, Wk, Wv, W1, W2, ln0g, ln0b,
                                          Wqt, Wkt, Wvt, W1t, W2t, yh, xh);
  qkv_kernel<<<dim3(128, 12), 256, 0, stream>>>(xh, yh, Wqt, Wkt, Wvt, bq, bk,
                                                bv, Qh, Kh, VhT);
  attn_kernel<<<1024, 256, 0, stream>>>(Qh, Kh, VhT, Ob);
  ln_kernel<<<RTOT / 4, 256, 0, stream>>>(Ob, ln1g, ln1b, Onh);
  mgemm_kernel<2><<<dim3(128, 8), 256, 0, stream>>>(Onh, W1t, b1, nullptr,
                                                    nullptr, Hidh, 256, 512);
  mgemm_kernel<3><<<dim3(128, 4), 256, 0, stream>>>(Hidh, W2t, b2, Ob, out,
                                                    nullptr, 512, 256);
}

// Round 8
// 222.576 us; speedup vs baseline: 1.3691x; 1.0176x over previous
//
#include <hip/hip_runtime.h>
#include <math.h>

// Problem constants (B=8, N=2048, D_IN=D_V=256, H=8, HD=32, D_FF=512)
#define RTOT 16384   // B*N rows
#define NSEQ 2048
#define NHEAD 8
#define HDIM 32
// Q pre-scale: log2(e)/sqrt(256) so S_mfma = S_true*log2e, softmax via exp2
#define QSCALE 0.09017132252479462f
#define QINV (1.0f / QSCALE)

typedef __attribute__((ext_vector_type(8))) short short8;
typedef __attribute__((ext_vector_type(4))) float f32x4;

#define GLOBAL_AS(p) ((__attribute__((address_space(1))) void*)(p))
#define LDS_AS(p) ((__attribute__((address_space(3))) void*)(p))

__device__ __forceinline__ unsigned pack_bf16(float a, float b) {
  unsigned ua = __float_as_uint(a) + 0x8000u;
  unsigned ub = __float_as_uint(b) + 0x8000u;
  return (ua >> 16) | (ub & 0xffff0000u);
}
// truncating pack via byte-perm (positive values; bias cancels in softmax ratio)
// result = [a.b2,a.b3,b.b2,b.b3] : low16 = bf16(a), high16 = bf16(b)
__device__ __forceinline__ unsigned pack_bf16_perm(float a, float b) {
  return __builtin_amdgcn_perm(__float_as_uint(b), __float_as_uint(a),
                               0x07060302u);
}
__device__ __forceinline__ ushort bf16_1(float a) {
  return (ushort)((__float_as_uint(a) + 0x8000u) >> 16);
}
__device__ __forceinline__ float bf16_to_f(ushort u) {
  return __uint_as_float(((unsigned)u) << 16);
}

// ---------------- stage0: fused weight-transpose + cvt(y) + ln0(x) ----------------
// blocks [0,112): weight transpose; [112,4208): y->bf16; [4208,8304): LN0(x)->bf16
__global__ __launch_bounds__(256) void stage0_kernel(
    const float* __restrict__ x, const float* __restrict__ y,
    const float* __restrict__ Wq, const float* __restrict__ Wk,
    const float* __restrict__ Wv, const float* __restrict__ W1,
    const float* __restrict__ W2, const float* __restrict__ ln0g,
    const float* __restrict__ ln0b, ushort* __restrict__ Wqt,
    ushort* __restrict__ Wkt, ushort* __restrict__ Wvt,
    ushort* __restrict__ W1t, ushort* __restrict__ W2t,
    ushort* __restrict__ yh, ushort* __restrict__ xh) {
  const int bid = blockIdx.x;
  const int t = threadIdx.x;
  if (bid < 112) {
    const float* W;
    ushort* Wt;
    int K, N, tile;
    if (bid < 16) { W = Wq; Wt = Wqt; K = 256; N = 256; tile = bid; }
    else if (bid < 32) { W = Wk; Wt = Wkt; K = 256; N = 256; tile = bid - 16; }
    else if (bid < 48) { W = Wv; Wt = Wvt; K = 256; N = 256; tile = bid - 32; }
    else if (bid < 80) { W = W1; Wt = W1t; K = 256; N = 512; tile = bid - 48; }
    else { W = W2; Wt = W2t; K = 512; N = 256; tile = bid - 80; }
    const int tn = N >> 6;
    const int k0 = (tile / tn) << 6, n0 = (tile % tn) << 6;
    __shared__ float T[64][65];
#pragma unroll
    for (int i = 0; i < 16; ++i) {
      const int idx = t + i * 256;
      const int r = idx >> 6, c = idx & 63;
      T[r][c] = W[(size_t)(k0 + r) * N + n0 + c];
    }
    __syncthreads();
#pragma unroll
    for (int i = 0; i < 16; ++i) {
      const int idx = t + i * 256;
      const int r = idx >> 6, c = idx & 63;
      Wt[(size_t)(n0 + r) * K + k0 + c] = bf16_1(T[c][r]);
    }
  } else if (bid < 4208) {
    const size_t i = ((size_t)(bid - 112) * 256 + t) * 4;
    const float4 v = *(const float4*)&y[i];
    uint2 pk;
    pk.x = pack_bf16(v.x, v.y);
    pk.y = pack_bf16(v.z, v.w);
    *(uint2*)&yh[i] = pk;
  } else {
    const int lane = t & 63, wave = t >> 6;
    const size_t row = (size_t)(bid - 4208) * 4 + wave;
    const float* xr = x + row * 256;
    float4 v = *(const float4*)&xr[lane * 4];
    float s = v.x + v.y + v.z + v.w;
#pragma unroll
    for (int m = 1; m < 64; m <<= 1) s += __shfl_xor(s, m, 64);
    const float mu = s * (1.0f / 256.0f);
    const float dx = v.x - mu, dy = v.y - mu, dz = v.z - mu, dw = v.w - mu;
    float ss = dx * dx + dy * dy + dz * dz + dw * dw;
#pragma unroll
    for (int m = 1; m < 64; m <<= 1) ss += __shfl_xor(ss, m, 64);
    const float rstd = rsqrtf(ss * (1.0f / 256.0f) + 1e-5f);
    const float4 gv = *(const float4*)&ln0g[lane * 4];
    const float4 bv = *(const float4*)&ln0b[lane * 4];
    uint2 pk;
    pk.x = pack_bf16(dx * rstd * gv.x + bv.x, dy * rstd * gv.y + bv.y);
    pk.y = pack_bf16(dz * rstd * gv.z + bv.z, dw * rstd * gv.w + bv.w);
    *(uint2*)&xh[row * 256 + lane * 4] = pk;
  }
}

// ---------------- LayerNorm over D=256, bf16 output ----------------
__global__ __launch_bounds__(256) void ln_kernel(
    const float* __restrict__ X, const float* __restrict__ g,
    const float* __restrict__ bt, ushort* __restrict__ Yh) {
  const int lane = threadIdx.x & 63;
  const int wave = threadIdx.x >> 6;
  const size_t row = (size_t)blockIdx.x * 4 + wave;
  const float* xr = X + row * 256;
  float4 v = *(const float4*)&xr[lane * 4];
  float s = v.x + v.y + v.z + v.w;
#pragma unroll
  for (int m = 1; m < 64; m <<= 1) s += __shfl_xor(s, m, 64);
  const float mu = s * (1.0f / 256.0f);
  const float dx = v.x - mu, dy = v.y - mu, dz = v.z - mu, dw = v.w - mu;
  float ss = dx * dx + dy * dy + dz * dz + dw * dw;
#pragma unroll
  for (int m = 1; m < 64; m <<= 1) ss += __shfl_xor(ss, m, 64);
  const float rstd = rsqrtf(ss * (1.0f / 256.0f) + 1e-5f);
  const float4 gv = *(const float4*)&g[lane * 4];
  const float4 bv = *(const float4*)&bt[lane * 4];
  uint2 pk;
  pk.x = pack_bf16(dx * rstd * gv.x + bv.x, dy * rstd * gv.y + bv.y);
  pk.y = pack_bf16(dz * rstd * gv.z + bv.z, dw * rstd * gv.w + bv.w);
  *(uint2*)&Yh[row * 256 + lane * 4] = pk;
}

// ---------------- merged QKV GEMM ----------------
// grid (128, 12): ny>>2 = 0:K 1:V 2:Q ; 128x64 tile, BK=32, 4 waves.
// K: Kh=bf16(v) ; Q: Qh=bf16(v*QSCALE) ; V: transpose -> VhT[b*256+n][nseq]
__global__ __launch_bounds__(256) void qkv_kernel(
    const ushort* __restrict__ xh, const ushort* __restrict__ yh,
    const ushort* __restrict__ Wqt, const ushort* __restrict__ Wkt,
    const ushort* __restrict__ Wvt, const float* __restrict__ bq,
    const float* __restrict__ bk, const float* __restrict__ bv,
    ushort* __restrict__ Qh, ushort* __restrict__ Kh,
    ushort* __restrict__ VhT) {
  __shared__ union UU {
    struct { ushort As[128 * 32]; ushort Bs[64 * 32]; } s;
    ushort Ct[64 * 136];  // V-transpose tile [n_local][m_local]
  } u;
  const int t = threadIdx.x;
  const int lane = t & 63, wave = t >> 6;
  const int l16 = lane & 15, quad = lane >> 4;
  const int row0 = blockIdx.x * 128;
  const int ny = blockIdx.y;
  const int which = ny >> 2;  // 0=K 1=V 2=Q
  const int n0 = (ny & 3) << 6;
  const ushort* A = (which == 2) ? xh : yh;
  const ushort* W = (which == 0) ? Wkt : (which == 1) ? Wvt : Wqt;
  const float* bs = (which == 0) ? bk : (which == 1) ? bv : bq;
  const int mrow = (wave & 1) * 64, ncol = (wave >> 1) * 32;

  const ushort* gA0 = A + (size_t)(row0 + (t >> 2)) * 256 + ((t & 3) << 3);
  const ushort* gA1 = gA0 + (size_t)64 * 256;
  const ushort* gB = W + (size_t)(n0 + (t >> 2)) * 256 + ((t & 3) << 3);
  ushort* lA0 = u.s.As + 8 * t;
  ushort* lA1 = u.s.As + 2048 + 8 * t;
  ushort* lB = u.s.Bs + 8 * t;

  f32x4 acc[4][2] = {};
  for (int kc = 0; kc < 256; kc += 32) {
    __builtin_amdgcn_global_load_lds(GLOBAL_AS(gA0 + kc), LDS_AS(lA0), 16, 0, 0);
    __builtin_amdgcn_global_load_lds(GLOBAL_AS(gA1 + kc), LDS_AS(lA1), 16, 0, 0);
    __builtin_amdgcn_global_load_lds(GLOBAL_AS(gB + kc), LDS_AS(lB), 16, 0, 0);
    __syncthreads();
    short8 af[4], bfr[2];
#pragma unroll
    for (int mi = 0; mi < 4; ++mi)
      af[mi] = *(const short8*)&u.s.As[(mrow + mi * 16 + l16) * 32 + quad * 8];
#pragma unroll
    for (int nj = 0; nj < 2; ++nj)
      bfr[nj] = *(const short8*)&u.s.Bs[(ncol + nj * 16 + l16) * 32 + quad * 8];
#pragma unroll
    for (int mi = 0; mi < 4; ++mi)
#pragma unroll
      for (int nj = 0; nj < 2; ++nj)
        acc[mi][nj] = __builtin_amdgcn_mfma_f32_16x16x32_bf16(
            af[mi], bfr[nj], acc[mi][nj], 0, 0, 0);
    __syncthreads();
  }

  if (which == 1) {
    // V: bias + transpose via LDS, coalesced write to VhT[b*256+n][nseq]
#pragma unroll
    for (int nj = 0; nj < 2; ++nj) {
      const int nloc = ncol + nj * 16 + l16;
      const float bvv = bs[n0 + nloc];
#pragma unroll
      for (int mi = 0; mi < 4; ++mi)
#pragma unroll
        for (int r = 0; r < 4; ++r)
          u.Ct[nloc * 136 + mrow + mi * 16 + quad * 4 + r] =
              bf16_1(acc[mi][nj][r] + bvv);
    }
    __syncthreads();
    const int bb = row0 >> 11, ns0 = row0 & 2047;
#pragma unroll
    for (int i = 0; i < 4; ++i) {
      const int c = t + i * 256;
      const int rr = c >> 4, c8 = (c & 15) << 3;
      *(float4*)&VhT[(size_t)(bb * 256 + n0 + rr) * 2048 + ns0 + c8] =
          *(const float4*)&u.Ct[rr * 136 + c8];
    }
  } else {
#pragma unroll
    for (int nj = 0; nj < 2; ++nj) {
      const int n = n0 + ncol + nj * 16 + l16;
      const float bvv = bs[n];
#pragma unroll
      for (int mi = 0; mi < 4; ++mi) {
#pragma unroll
        for (int r = 0; r < 4; ++r) {
          const size_t m = (size_t)row0 + mrow + mi * 16 + quad * 4 + r;
          const float v = acc[mi][nj][r] + bvv;
          if (which == 2) Qh[m * 256 + n] = bf16_1(v * QSCALE);
          else Kh[m * 256 + n] = bf16_1(v);
        }
      }
    }
  }
}

// ---------------- FFN GEMM: 128x64 tile, BK=32 ----------------
// MODE 2: Ch=bf16(gelu(v)) (FFN1) ; MODE 3: Cf=v+res (FFN2 -> out)
template <int MODE>
__global__ __launch_bounds__(256) void mgemm_kernel(
    const ushort* __restrict__ A, const ushort* __restrict__ Wt,
    const float* __restrict__ bias, const float* __restrict__ res,
    float* __restrict__ Cf, ushort* __restrict__ Ch, int K, int N) {
  __shared__ ushort As[128 * 32];
  __shared__ ushort Bs[64 * 32];
  const int t = threadIdx.x;
  const int lane = t & 63, wave = t >> 6;
  const int l16 = lane & 15, quad = lane >> 4;
  const int row0 = blockIdx.x * 128;
  const int n0 = blockIdx.y << 6;
  const int mrow = (wave & 1) * 64, ncol = (wave >> 1) * 32;

  const ushort* gA0 = A + (size_t)(row0 + (t >> 2)) * K + ((t & 3) << 3);
  const ushort* gA1 = gA0 + (size_t)64 * K;
  const ushort* gB = Wt + (size_t)(n0 + (t >> 2)) * K + ((t & 3) << 3);
  ushort* lA0 = As + 8 * t;
  ushort* lA1 = As + 2048 + 8 * t;
  ushort* lB = Bs + 8 * t;

  f32x4 acc[4][2] = {};
  for (int kc = 0; kc < K; kc += 32) {
    __builtin_amdgcn_global_load_lds(GLOBAL_AS(gA0 + kc), LDS_AS(lA0), 16, 0, 0);
    __builtin_amdgcn_global_load_lds(GLOBAL_AS(gA1 + kc), LDS_AS(lA1), 16, 0, 0);
    __builtin_amdgcn_global_load_lds(GLOBAL_AS(gB + kc), LDS_AS(lB), 16, 0, 0);
    __syncthreads();
    short8 af[4], bfr[2];
#pragma unroll
    for (int mi = 0; mi < 4; ++mi)
      af[mi] = *(const short8*)&As[(mrow + mi * 16 + l16) * 32 + quad * 8];
#pragma unroll
    for (int nj = 0; nj < 2; ++nj)
      bfr[nj] = *(const short8*)&Bs[(ncol + nj * 16 + l16) * 32 + quad * 8];
#pragma unroll
    for (int mi = 0; mi < 4; ++mi)
#pragma unroll
      for (int nj = 0; nj < 2; ++nj)
        acc[mi][nj] = __builtin_amdgcn_mfma_f32_16x16x32_bf16(
            af[mi], bfr[nj], acc[mi][nj], 0, 0, 0);
    __syncthreads();
  }
#pragma unroll
  for (int nj = 0; nj < 2; ++nj) {
    const int n = n0 + ncol + nj * 16 + l16;
    const float bvv = bias[n];
#pragma unroll
    for (int mi = 0; mi < 4; ++mi) {
#pragma unroll
      for (int r = 0; r < 4; ++r) {
        const size_t m = (size_t)row0 + mrow + mi * 16 + quad * 4 + r;
        float v = acc[mi][nj][r] + bvv;
        if (MODE == 2) {
          v = 0.5f * v * (1.0f + erff(v * 0.70710678118654752f));
          Ch[m * N + n] = bf16_1(v);
        }
        if (MODE == 3) Cf[m * N + n] = v + res[m * N + n];
      }
    }
  }
}

// ---------------- Flash attention (bf16 MFMA, zero-max, 128q, pipelined groups) ----
// O = Q + softmax(Q K^T / 16) V.  Qh pre-scaled by log2(e)/16 (bf16); residual
// recovered as Qh/QSCALE. No max shift (p = exp2(S*log2e), ratio-invariant);
// l via ones-MFMA. Wave: 2 groups of 16 q rows; kf/vf frags shared in regs.
// Grid 1024: bh = idx&63 (XCD swizzle), qt = idx>>6.
__global__ __launch_bounds__(256) void attn_kernel(
    const ushort* __restrict__ Qh, const ushort* __restrict__ Kh,
    const ushort* __restrict__ VhT, float* __restrict__ O) {
  __shared__ ushort Ks[2][64][40];      // 10240 B
  __shared__ ushort Vt[2][32][72];      // 9216 B
  __shared__ ushort Pl[4][2][16][72];   // 18432 B  (per-wave, per-group)

  const int t = threadIdx.x;
  const int lane = t & 63, wave = t >> 6;
  const int l16 = lane & 15, quad = lane >> 4;
  const int bh = blockIdx.x & 63;
  const int qt = blockIdx.x >> 6;  // 0..15
  const int b = bh >> 3, h = bh & 7;

  const size_t rowQ0 = (size_t)(b * NSEQ + qt * 128 + wave * 32 + l16);
  const short8 qfrag0 = *(const short8*)&Qh[rowQ0 * 256 + h * HDIM + quad * 8];
  const short8 qfrag1 =
      *(const short8*)&Qh[(rowQ0 + 16) * 256 + h * HDIM + quad * 8];
  const short8 ones = {16256, 16256, 16256, 16256,
                       16256, 16256, 16256, 16256};  // bf16 1.0 x8
  const f32x4 zf = {0.f, 0.f, 0.f, 0.f};

  f32x4 o00 = zf, o01 = zf, o10 = zf, o11 = zf;
  f32x4 s0 = zf, s1 = zf;

  // staging coords (cooperative, coalesced): K tile [64][32], V tile [32][64]
  const int kr = t >> 2, kc8 = (t & 3) << 3;
  const int vd = t >> 3, vc8 = (t & 7) << 3;
  const ushort* gK = Kh + ((size_t)(b * NSEQ + kr)) * 256 + h * HDIM + kc8;
  const ushort* gV = VhT + ((size_t)(bh * 32 + vd)) * 2048 + vc8;

  float4 kreg = *(const float4*)gK;
  float4 vreg = *(const float4*)gV;

  for (int kt = 0; kt < 32; ++kt) {
    const int bf = kt & 1;
    *(float4*)&Ks[bf][kr][kc8] = kreg;
    *(float4*)&Vt[bf][vd][vc8] = vreg;
    __syncthreads();  // buf visible; prev readers done (prev barrier)
    if (kt < 31) {    // register prefetch, in flight over compute
      kreg = *(const float4*)(gK + (size_t)(kt + 1) * 64 * 256);
      vreg = *(const float4*)(gV + (kt + 1) * 64);
    }

    // shared fragments for both q-groups (wave-independent LDS reads)
    short8 kf[4];
#pragma unroll
    for (int sub = 0; sub < 4; ++sub)
      kf[sub] = *(const short8*)&Ks[bf][sub * 16 + l16][quad * 8];
    const short8 vf00 = *(const short8*)&Vt[bf][l16][quad * 8];
    const short8 vf01 = *(const short8*)&Vt[bf][l16][32 + quad * 8];
    const short8 vf10 = *(const short8*)&Vt[bf][16 + l16][quad * 8];
    const short8 vf11 = *(const short8*)&Vt[bf][16 + l16][32 + quad * 8];

    // ---- S-MFMAs for BOTH groups (MFMA latency overlaps exp2 below) ----
    f32x4 sa0[4], sa1[4];
#pragma unroll
    for (int sub = 0; sub < 4; ++sub)
      sa0[sub] =
          __builtin_amdgcn_mfma_f32_16x16x32_bf16(kf[sub], qfrag0, zf, 0, 0, 0);
#pragma unroll
    for (int sub = 0; sub < 4; ++sub)
      sa1[sub] =
          __builtin_amdgcn_mfma_f32_16x16x32_bf16(kf[sub], qfrag1, zf, 0, 0, 0);

    // ---- exp2 + perm-pack both groups, single fence ----
#pragma unroll
    for (int sub = 0; sub < 4; ++sub) {
      uint2 pk;
      pk.x = pack_bf16_perm(__builtin_amdgcn_exp2f(sa0[sub][0]),
                            __builtin_amdgcn_exp2f(sa0[sub][1]));
      pk.y = pack_bf16_perm(__builtin_amdgcn_exp2f(sa0[sub][2]),
                            __builtin_amdgcn_exp2f(sa0[sub][3]));
      *(uint2*)&Pl[wave][0][l16][sub * 16 + quad * 4] = pk;
    }
#pragma unroll
    for (int sub = 0; sub < 4; ++sub) {
      uint2 pk;
      pk.x = pack_bf16_perm(__builtin_amdgcn_exp2f(sa1[sub][0]),
                            __builtin_amdgcn_exp2f(sa1[sub][1]));
      pk.y = pack_bf16_perm(__builtin_amdgcn_exp2f(sa1[sub][2]),
                            __builtin_amdgcn_exp2f(sa1[sub][3]));
      *(uint2*)&Pl[wave][1][l16][sub * 16 + quad * 4] = pk;
    }
    __threadfence_block();  // one lgkm drain; Pl is wave-private

    // ---- PV + row-sum MFMAs, both groups ----
    const short8 pf00 = *(const short8*)&Pl[wave][0][l16][quad * 8];
    const short8 pf01 = *(const short8*)&Pl[wave][0][l16][32 + quad * 8];
    const short8 pf10 = *(const short8*)&Pl[wave][1][l16][quad * 8];
    const short8 pf11 = *(const short8*)&Pl[wave][1][l16][32 + quad * 8];
    o00 = __builtin_amdgcn_mfma_f32_16x16x32_bf16(pf00, vf00, o00, 0, 0, 0);
    o00 = __builtin_amdgcn_mfma_f32_16x16x32_bf16(pf01, vf01, o00, 0, 0, 0);
    o01 = __builtin_amdgcn_mfma_f32_16x16x32_bf16(pf00, vf10, o01, 0, 0, 0);
    o01 = __builtin_amdgcn_mfma_f32_16x16x32_bf16(pf01, vf11, o01, 0, 0, 0);
    o10 = __builtin_amdgcn_mfma_f32_16x16x32_bf16(pf10, vf00, o10, 0, 0, 0);
    o10 = __builtin_amdgcn_mfma_f32_16x16x32_bf16(pf11, vf01, o10, 0, 0, 0);
    o11 = __builtin_amdgcn_mfma_f32_16x16x32_bf16(pf10, vf10, o11, 0, 0, 0);
    o11 = __builtin_amdgcn_mfma_f32_16x16x32_bf16(pf11, vf11, o11, 0, 0, 0);
    s0 = __builtin_amdgcn_mfma_f32_16x16x32_bf16(pf00, ones, s0, 0, 0, 0);
    s0 = __builtin_amdgcn_mfma_f32_16x16x32_bf16(pf01, ones, s0, 0, 0, 0);
    s1 = __builtin_amdgcn_mfma_f32_16x16x32_bf16(pf10, ones, s1, 0, 0, 0);
    s1 = __builtin_amdgcn_mfma_f32_16x16x32_bf16(pf11, ones, s1, 0, 0, 0);
  }

  // ---- epilogue: O = Q + oacc/l ; Q routed via wave-private LDS ----
  __threadfence_block();
  *(short8*)&Pl[wave][0][l16][quad * 8] = qfrag0;
  *(short8*)&Pl[wave][1][l16][quad * 8] = qfrag1;
  __threadfence_block();
#pragma unroll
  for (int g = 0; g < 2; ++g) {
    const f32x4 oS = g ? s1 : s0;
    const f32x4 oa = g ? o10 : o00;
    const f32x4 ob = g ? o11 : o01;
    const size_t row0 =
        (size_t)(b * NSEQ + qt * 128 + wave * 32 + g * 16 + quad * 4);
#pragma unroll
    for (int r = 0; r < 4; ++r) {
      const float q0 = bf16_to_f(Pl[wave][g][quad * 4 + r][l16]) * QINV;
      const float q1 = bf16_to_f(Pl[wave][g][quad * 4 + r][16 + l16]) * QINV;
      const float il = 1.0f / oS[r];
      const size_t ro = (row0 + r) * 256 + h * HDIM + l16;
      O[ro] = q0 + oa[r] * il;
      O[ro + 16] = q1 + ob[r] * il;
    }
  }
}

extern "C" void kernel_launch(void* const* d_in, const int* in_sizes, int n_in,
                              void* d_out, int out_size, void* d_ws, size_t ws_size,
                              hipStream_t stream) {
  const float* x = (const float*)d_in[0];
  const float* y = (const float*)d_in[1];
  const float* Wq = (const float*)d_in[2];
  const float* bq = (const float*)d_in[3];
  const float* Wk = (const float*)d_in[4];
  const float* bk = (const float*)d_in[5];
  const float* Wv = (const float*)d_in[6];
  const float* bv = (const float*)d_in[7];
  const float* W1 = (const float*)d_in[8];
  const float* b1 = (const float*)d_in[9];
  const float* W2 = (const float*)d_in[10];
  const float* b2 = (const float*)d_in[11];
  const float* ln0g = (const float*)d_in[12];
  const float* ln0b = (const float*)d_in[13];
  const float* ln1g = (const float*)d_in[14];
  const float* ln1b = (const float*)d_in[15];
  float* out = (float*)d_out;
  char* base = (char*)d_ws;

  const size_t RM = (size_t)RTOT * 256;
  // region0: yh (bf16, stage0->qkv) then overwritten by Ob (fp32, attn out)
  ushort* yh = (ushort*)base;
  float* Ob = (float*)base;
  ushort* Qh = (ushort*)(base + 2 * RM * 4);
  ushort* Kh = (ushort*)(base + 2 * RM * 4 + RM * 2);
  ushort* VhT = (ushort*)(base + 3 * RM * 4);
  ushort* xh = (ushort*)(base + 3 * RM * 4 + RM * 2);  // LN0 out; reused as On
  ushort* Onh = xh;
  ushort* Hidh = Qh;  // [R,512] bf16 overlays Qh+Kh (dead after attn)
  char* wbase = base + 4 * RM * 4;
  ushort* Wqt = (ushort*)wbase;  // [256,256]
  ushort* Wkt = Wqt + 65536;
  ushort* Wvt = Wkt + 65536;
  ushort* W1t = Wvt + 65536;   // [512,256]
  ushort* W2t = W1t + 131072;  // [256,512]

  stage0_kernel<<<8304, 256, 0, stream>>>(x, y, Wq, Wk, Wv, W1, W2, ln0g, ln0b,
                                          Wqt, Wkt, Wvt, W1t, W2t, yh, xh);
  qkv_kernel<<<dim3(128, 12), 256, 0, stream>>>(xh, yh, Wqt, Wkt, Wvt, bq, bk,
                                                bv, Qh, Kh, VhT);
  attn_kernel<<<1024, 256, 0, stream>>>(Qh, Kh, VhT, Ob);
  ln_kernel<<<RTOT / 4, 256, 0, stream>>>(Ob, ln1g, ln1b, Onh);
  mgemm_kernel<2><<<dim3(128, 8), 256, 0, stream>>>(Onh, W1t, b1, nullptr,
                                                    nullptr, Hidh, 256, 512);
  mgemm_kernel<3><<<dim3(128, 4), 256, 0, stream>>>(Hidh, W2t, b2, Ob, out,
                                                    nullptr, 512, 256);
}